// Round 1
// baseline (137.339 us; speedup 1.0000x reference)
//
#include <hip/hip_runtime.h>

// FFM pairwise interaction: out[b] = sum_{i<j} sum_k in[b,i,j,k] * in[b,j,i,k]
// B=8192, F=39, K=16, fp32 in/out. Memory-bound: ~780MB read once.

#define FF    39
#define KK    16
#define NPAIR (FF * (FF - 1) / 2)   // 741
#define SLICE (FF * FF * KK)        // 24336 floats per batch
#define ITEMS (NPAIR * 4)           // 2964 float4 work items per batch
#define NTHR  256

__global__ __launch_bounds__(NTHR) void ffm_kernel(const float* __restrict__ in,
                                                   float* __restrict__ out,
                                                   int nbatch) {
    __shared__ int xoff[NPAIR];   // element offset of [i,j,0]
    __shared__ int yoff[NPAIR];   // element offset of [j,i,0]
    __shared__ float red[NTHR / 64];

    const int tid = threadIdx.x;

    // Build pair -> offset table once per block (~741 entries).
    for (int p = tid; p < NPAIR; p += NTHR) {
        int pp = p, i = 0;
        while (pp >= FF - 1 - i) { pp -= FF - 1 - i; ++i; }
        int j = i + 1 + pp;
        xoff[p] = (i * FF + j) * KK;
        yoff[p] = (j * FF + i) * KK;
    }
    __syncthreads();

    // Grid-stride over batches (one block handles one batch per iteration).
    for (int b = blockIdx.x; b < nbatch; b += gridDim.x) {
        const float* base = in + (size_t)b * SLICE;
        float acc = 0.f;

        // 2964 float4-dot items: item -> (pair p, quad q).
        for (int item = tid; item < ITEMS; item += NTHR) {
            int p = item >> 2;
            int q = (item & 3) * 4;
            const float4 x = *reinterpret_cast<const float4*>(base + xoff[p] + q);
            const float4 y = *reinterpret_cast<const float4*>(base + yoff[p] + q);
            acc += x.x * y.x + x.y * y.y + x.z * y.z + x.w * y.w;
        }

        // Wave (64-lane) shuffle reduce.
        #pragma unroll
        for (int off = 32; off > 0; off >>= 1)
            acc += __shfl_down(acc, off, 64);

        const int wave = tid >> 6;
        if ((tid & 63) == 0) red[wave] = acc;
        __syncthreads();
        if (tid == 0) {
            float s = 0.f;
            #pragma unroll
            for (int w = 0; w < NTHR / 64; ++w) s += red[w];
            out[b] = s;
        }
        __syncthreads();  // protect red[] before next batch iteration
    }
}

extern "C" void kernel_launch(void* const* d_in, const int* in_sizes, int n_in,
                              void* d_out, int out_size, void* d_ws, size_t ws_size,
                              hipStream_t stream) {
    const float* in = (const float*)d_in[0];
    float* out = (float*)d_out;
    const int nbatch = out_size;  // 8192, out shape [B,1]

    dim3 grid(nbatch);
    dim3 block(NTHR);
    ffm_kernel<<<grid, block, 0, stream>>>(in, out, nbatch);
}